// Round 1
// baseline (532.096 us; speedup 1.0000x reference)
//
#include <hip/hip_runtime.h>

// MultiAttention: B=32768 batches, HOP=32, D=64.
// score[b,h] = sum_d tanh((rel[b,h]@w_r)[d])*va[64+d] + tanh((nbr[b,h]@w_t)[d])*va[128+d]
// out = softmax over h.  (entity/w_h are dead: head branch is tanh(0)=0.)
// Strategy: split-bf16 (hi+lo, 3 MFMAs) 16x16x32 MFMA -> fp32-accurate, memory-bound.

typedef short bf16x8 __attribute__((ext_vector_type(8)));
typedef float f32x4 __attribute__((ext_vector_type(4)));

#define NB   32768
#define NHOP 32
#define ND   64

__device__ __forceinline__ float tanh_fast(float x) {
  float cx = fminf(fmaxf(x, -20.f), 20.f);
  float e2 = __expf(2.f * cx);
  return (e2 - 1.f) * __builtin_amdgcn_rcpf(e2 + 1.f);
}

// split 8 fp32 (two float4, consecutive k) into bf16 hi (truncate) + lo (residual)
__device__ __forceinline__ void split2(float4 v0, float4 v1, bf16x8 &hi, bf16x8 &lo) {
  float xs[8] = {v0.x, v0.y, v0.z, v0.w, v1.x, v1.y, v1.z, v1.w};
#pragma unroll
  for (int j = 0; j < 8; ++j) {
    unsigned u = __builtin_bit_cast(unsigned, xs[j]);
    hi[j] = (short)(u >> 16);
    float hif = __builtin_bit_cast(float, u & 0xffff0000u);
    lo[j] = (short)(__builtin_bit_cast(unsigned, xs[j] - hif) >> 16);
  }
}

__global__ __launch_bounds__(256, 2)
void attn_fused(const float* __restrict__ rel, const float* __restrict__ nbr,
                const float* __restrict__ wr, const float* __restrict__ wt,
                const float* __restrict__ va, float* __restrict__ out, int nwaves) {
  const int lane = threadIdx.x & 63;
  const int wid  = (blockIdx.x * blockDim.x + threadIdx.x) >> 6;
  const int l15  = lane & 15;   // A-frag row m / C col / B col n
  const int lg   = lane >> 4;   // k-chunk group; C row group

  // W fragments (B operand): lane holds W[c*32 + lg*8 + j][nt*16 + l15], hi+lo.
  // 2 mats x 2 kchunks x 4 ntiles x 2 halves = 32 frags = 128 VGPRs. Loaded once per wave.
  bf16x8 wf[2][2][4][2];
#pragma unroll
  for (int mat = 0; mat < 2; ++mat) {
    const float* W = mat ? wt : wr;
#pragma unroll
    for (int c = 0; c < 2; ++c)
#pragma unroll
      for (int nt = 0; nt < 4; ++nt) {
        bf16x8 hi, lo;
#pragma unroll
        for (int j = 0; j < 8; ++j) {
          float x = W[(c * 32 + lg * 8 + j) * 64 + nt * 16 + l15];
          unsigned u = __builtin_bit_cast(unsigned, x);
          hi[j] = (short)(u >> 16);
          float hif = __builtin_bit_cast(float, u & 0xffff0000u);
          lo[j] = (short)(__builtin_bit_cast(unsigned, x - hif) >> 16);
        }
        wf[mat][c][nt][0] = hi;
        wf[mat][c][nt][1] = lo;
      }
  }

  float va1[4], va2[4];
#pragma unroll
  for (int nt = 0; nt < 4; ++nt) {
    va1[nt] = va[64 + nt * 16 + l15];
    va2[nt] = va[128 + nt * 16 + l15];
  }

  for (int b = wid; b < NB; b += nwaves) {
    float sc[2][4];  // scores for rows tt*16 + lg*4 + rr (all l15 duplicated)
#pragma unroll
    for (int tt = 0; tt < 2; ++tt) {
      const size_t row = (size_t)b * NHOP + tt * 16 + l15;
      const float* rbase = rel + row * ND + lg * 8;
      const float* tbase = nbr + row * ND + lg * 8;
      float4 r0 = *(const float4*)(rbase);
      float4 r1 = *(const float4*)(rbase + 4);
      float4 r2 = *(const float4*)(rbase + 32);
      float4 r3 = *(const float4*)(rbase + 36);
      float4 t0 = *(const float4*)(tbase);
      float4 t1 = *(const float4*)(tbase + 4);
      float4 t2 = *(const float4*)(tbase + 32);
      float4 t3 = *(const float4*)(tbase + 36);

      f32x4 part = {0.f, 0.f, 0.f, 0.f};

      // --- relation @ w_r ---
      {
        bf16x8 ahi[2], alo[2];
        split2(r0, r1, ahi[0], alo[0]);
        split2(r2, r3, ahi[1], alo[1]);
        f32x4 acc[4];
#pragma unroll
        for (int nt = 0; nt < 4; ++nt) acc[nt] = (f32x4){0.f, 0.f, 0.f, 0.f};
#pragma unroll
        for (int c = 0; c < 2; ++c)
#pragma unroll
          for (int nt = 0; nt < 4; ++nt) {
            acc[nt] = __builtin_amdgcn_mfma_f32_16x16x32_bf16(ahi[c], wf[0][c][nt][0], acc[nt], 0, 0, 0);
            acc[nt] = __builtin_amdgcn_mfma_f32_16x16x32_bf16(alo[c], wf[0][c][nt][0], acc[nt], 0, 0, 0);
            acc[nt] = __builtin_amdgcn_mfma_f32_16x16x32_bf16(ahi[c], wf[0][c][nt][1], acc[nt], 0, 0, 0);
          }
#pragma unroll
        for (int nt = 0; nt < 4; ++nt)
#pragma unroll
          for (int rr = 0; rr < 4; ++rr)
            part[rr] += tanh_fast(acc[nt][rr]) * va1[nt];
      }

      // --- neighbor @ w_t ---
      {
        bf16x8 ahi[2], alo[2];
        split2(t0, t1, ahi[0], alo[0]);
        split2(t2, t3, ahi[1], alo[1]);
        f32x4 acc[4];
#pragma unroll
        for (int nt = 0; nt < 4; ++nt) acc[nt] = (f32x4){0.f, 0.f, 0.f, 0.f};
#pragma unroll
        for (int c = 0; c < 2; ++c)
#pragma unroll
          for (int nt = 0; nt < 4; ++nt) {
            acc[nt] = __builtin_amdgcn_mfma_f32_16x16x32_bf16(ahi[c], wf[1][c][nt][0], acc[nt], 0, 0, 0);
            acc[nt] = __builtin_amdgcn_mfma_f32_16x16x32_bf16(alo[c], wf[1][c][nt][0], acc[nt], 0, 0, 0);
            acc[nt] = __builtin_amdgcn_mfma_f32_16x16x32_bf16(ahi[c], wf[1][c][nt][1], acc[nt], 0, 0, 0);
          }
#pragma unroll
        for (int nt = 0; nt < 4; ++nt)
#pragma unroll
          for (int rr = 0; rr < 4; ++rr)
            part[rr] += tanh_fast(acc[nt][rr]) * va2[nt];
      }

      // column reduction: sum over the 16 lanes sharing a C-row group
#pragma unroll
      for (int m = 1; m <= 8; m <<= 1)
#pragma unroll
        for (int rr = 0; rr < 4; ++rr)
          part[rr] += __shfl_xor(part[rr], m, 64);
#pragma unroll
      for (int rr = 0; rr < 4; ++rr) sc[tt][rr] = part[rr];
    }

    // softmax over the 32 hops: local max over 8 regs, then across the 4 groups
    float smax = fmaxf(fmaxf(sc[0][0], sc[0][1]), fmaxf(sc[0][2], sc[0][3]));
    smax = fmaxf(smax, fmaxf(fmaxf(sc[1][0], sc[1][1]), fmaxf(sc[1][2], sc[1][3])));
    smax = fmaxf(smax, __shfl_xor(smax, 16, 64));
    smax = fmaxf(smax, __shfl_xor(smax, 32, 64));

    float e[2][4];
    float ssum = 0.f;
#pragma unroll
    for (int tt = 0; tt < 2; ++tt)
#pragma unroll
      for (int rr = 0; rr < 4; ++rr) {
        e[tt][rr] = __expf(sc[tt][rr] - smax);
        ssum += e[tt][rr];
      }
    ssum += __shfl_xor(ssum, 16, 64);
    ssum += __shfl_xor(ssum, 32, 64);
    float inv = __builtin_amdgcn_rcpf(ssum);

    if (l15 == 0) {  // one writer lane per group; rows lg*4+rr are contiguous -> float4
      float* ob = out + (size_t)b * NHOP;
      float4 o0 = {e[0][0] * inv, e[0][1] * inv, e[0][2] * inv, e[0][3] * inv};
      float4 o1 = {e[1][0] * inv, e[1][1] * inv, e[1][2] * inv, e[1][3] * inv};
      *(float4*)(ob + lg * 4)      = o0;
      *(float4*)(ob + 16 + lg * 4) = o1;
    }
  }
}

extern "C" void kernel_launch(void* const* d_in, const int* in_sizes, int n_in,
                              void* d_out, int out_size, void* d_ws, size_t ws_size,
                              hipStream_t stream) {
  // inputs: 0 entity (dead), 1 relation, 2 neighbor, 3 w_h (dead), 4 w_t, 5 w_r, 6 v_a
  const float* rel = (const float*)d_in[1];
  const float* nbr = (const float*)d_in[2];
  const float* wt  = (const float*)d_in[4];
  const float* wr  = (const float*)d_in[5];
  const float* va  = (const float*)d_in[6];
  float* out = (float*)d_out;

  const int blocks = 1024;                 // 4096 waves, 8 batches each (exact)
  attn_fused<<<blocks, 256, 0, stream>>>(rel, nbr, wr, wt, va, out, blocks * 4);
}